// Round 4
// baseline (76.921 us; speedup 1.0000x reference)
//
#include <hip/hip_runtime.h>
#include <stdint.h>

#define NUM_LEVELS 21
#define BB 8
#define T 256
#define C 16
#define D 4096
#define DC 16            // d-outputs per block
#define COLS 19          // DC + 3 cyclic halo
#define QSTRIDE 20       // u32 per quad row (19 used + 1 pad)
#define QROWS 66         // 64 quads + 2 pad rows (tail overread)

// ws layout (u32 words):
//   [0     .. 8192)  packed idx bytes: [b][t][c/4]   (8*256*4 words = 32 KB)
//   [8192  .. 12288) lwbits[d]  (21-bit sign word per d)
//   [12288 .. 16384) cwbits[d]  (16-bit sign word per d)
#define WS_IDX 0
#define WS_LW  8192
#define WS_CW  12288

__global__ __launch_bounds__(256)
void prep_kernel(const float* __restrict__ x,
                 const float* __restrict__ lw,
                 const float* __restrict__ cw,
                 uint32_t* __restrict__ ws) {
    const int blk = blockIdx.x, tid = threadIdx.x;
    if (blk < 32) {
        // quantize x -> packed idx (4 bytes per u32). W indexes u32 words.
        const int W = blk * 256 + tid;               // 0..8191
        const float4 v = *(const float4*)(x + 4 * W); // coalesced
        float vv[4] = {v.x, v.y, v.z, v.w};
        uint32_t pk = 0;
        #pragma unroll
        for (int e = 0; e < 4; ++e) {
            float fi = (vv[e] / 20.0f) * 20.0f;   // exact replica of np ops (IEEE f32)
            int id = (int)rintf(fi);              // half-to-even == np.round
            id = min(max(id, 0), NUM_LEVELS - 1);
            pk |= (uint32_t)id << (8 * e);
        }
        ws[WS_IDX + W] = pk;
    } else {
        // bit-pack weight sign columns; consecutive threads -> consecutive d (coalesced)
        const int d = (blk - 32) * 256 + tid;        // 0..4095
        uint32_t wl = 0;
        #pragma unroll
        for (int l = 0; l < NUM_LEVELS; ++l)
            wl |= (__float_as_uint(lw[l * D + d]) >> 31) << l;   // bit = (w<0)
        ws[WS_LW + d] = wl;
        uint32_t wc = 0;
        #pragma unroll
        for (int c = 0; c < C; ++c)
            wc |= (__float_as_uint(cw[c * D + d]) >> 31) << c;
        ws[WS_CW + d] = wc;
    }
}

__global__ __launch_bounds__(256)
void encoder_kernel(const uint32_t* __restrict__ ws,
                    float* __restrict__ out) {
    __shared__ uint32_t sampQ[QROWS * QSTRIDE];   // 5280 B
    __shared__ int      part[15 * DC];            // 960 B

    const int tid = threadIdx.x;
    const int b   = blockIdx.x >> 8;
    const int d0  = (blockIdx.x & 255) * DC;

    // ---- Phase 1: thread = (quad q, colgroup g); 4 t's x 5 cols each.
    // s[t][col] = 16 - 2*popc(mask ^ cw16), packed 4 t-bytes per u32.
    {
        const int q = tid >> 2;            // 0..63
        const int g = tid & 3;             // 0..3
        uint32_t lc[5], cc[5];
        #pragma unroll
        for (int k = 0; k < 5; ++k) {
            int col = 5 * g + k; col = col > 18 ? 18 : col;   // clamp-dup, benign
            int d = (d0 - 3 + col) & (D - 1);
            lc[k] = ws[WS_LW + d];     // L2-hit
            cc[k] = ws[WS_CW + d];
        }
        uint32_t accum[5] = {0, 0, 0, 0, 0};
        #pragma unroll
        for (int tp = 0; tp < 4; ++tp) {
            const int t = 4 * q + tp;
            const uint4 row = *(const uint4*)(ws + WS_IDX + b * 1024 + t * 4);
            int l[16];
            #pragma unroll
            for (int e = 0; e < 4; ++e) {
                l[e]      = (row.x >> (8 * e)) & 31;
                l[4 + e]  = (row.y >> (8 * e)) & 31;
                l[8 + e]  = (row.z >> (8 * e)) & 31;
                l[12 + e] = (row.w >> (8 * e)) & 31;
            }
            #pragma unroll
            for (int k = 0; k < 5; ++k) {
                uint32_t m = 0;
                #pragma unroll
                for (int c = 0; c < 16; ++c)
                    m |= ((lc[k] >> l[c]) & 1u) << c;   // bfe + lshl_or
                int s = 16 - 2 * __popc(m ^ cc[k]);
                accum[k] |= (uint32_t)(uint8_t)(int8_t)s << (8 * tp);
            }
        }
        #pragma unroll
        for (int k = 0; k < 5; ++k) {
            int col = 5 * g + k; col = col > 18 ? 18 : col;
            sampQ[q * QSTRIDE + col] = accum[k];        // dup write = same value
        }
    }
    __syncthreads();

    // ---- Phase 2: thread = (col j, seg); diagonal 4-gram, sliding 2-reg window.
    // output d0+j uses samples (t+i, j+i), i=0..3 (j..j+3 in halo coords).
    const int j   = tid & 15;
    const int seg = tid >> 4;              // 0..15
    int acc = 0;
    {
        const int t0 = seg * 16;
        const int t1 = (t0 + 16 < 253) ? t0 + 16 : 253;
        const int q0 = t0 >> 2;
        uint32_t A[4], Bv[4];
        #pragma unroll
        for (int i = 0; i < 4; ++i) {
            A[i]  = sampQ[q0 * QSTRIDE + j + i];
            Bv[i] = sampQ[(q0 + 1) * QSTRIDE + j + i];
        }
        for (int t = t0; t < t1; t += 4) {
            uint32_t pk0 = A[0];
            uint32_t pk1 = (A[1] >> 8)  | (Bv[1] << 24);
            uint32_t pk2 = (A[2] >> 16) | (Bv[2] << 16);
            uint32_t pk3 = (A[3] >> 24) | (Bv[3] << 8);
            #pragma unroll
            for (int k = 0; k < 4; ++k) {
                if (t + k < t1) {
                    int s0 = (int)(int8_t)(pk0 >> (8 * k));
                    int s1 = (int)(int8_t)(pk1 >> (8 * k));
                    int s2 = (int)(int8_t)(pk2 >> (8 * k));
                    int s3 = (int)(int8_t)(pk3 >> (8 * k));
                    acc += (s0 * s1) * (s2 * s3);
                }
            }
            const int qn = (t >> 2) + 2;
            #pragma unroll
            for (int i = 0; i < 4; ++i) {
                A[i]  = Bv[i];
                Bv[i] = sampQ[qn * QSTRIDE + j + i];   // tail overread hits pad rows
            }
        }
    }
    if (seg) part[(seg - 1) * DC + j] = acc;
    __syncthreads();

    // ---- Final reduce + sign
    if (seg == 0) {
        int hv = acc;
        #pragma unroll
        for (int s = 0; s < 15; ++s) hv += part[s * DC + j];
        out[b * D + d0 + j] = hv > 0 ? 1.0f : -1.0f;   // hv==0 -> -1, matches ref
    }
}

extern "C" void kernel_launch(void* const* d_in, const int* in_sizes, int n_in,
                              void* d_out, int out_size, void* d_ws, size_t ws_size,
                              hipStream_t stream) {
    const float* x  = (const float*)d_in[0];
    const float* lw = (const float*)d_in[1];
    const float* cw = (const float*)d_in[2];
    float* out = (float*)d_out;
    uint32_t* ws = (uint32_t*)d_ws;

    prep_kernel<<<48, 256, 0, stream>>>(x, lw, cw, ws);
    encoder_kernel<<<BB * (D / DC), 256, 0, stream>>>(ws, out);  // 2048 blocks
}

// Round 5
// 64.108 us; speedup vs baseline: 1.1999x; 1.1999x over previous
//
#include <hip/hip_runtime.h>
#include <stdint.h>

#define NUM_LEVELS 21
#define BB 8
#define T 256
#define C 16
#define D 4096
#define NW 128          // 32-d words covering D
#define SROW 9          // u32 per sample-count row (36 byte-cols, 35 used)

// Full/half adders on 32 bit-lanes (one lane per d)
#define FA(a,b,c,sum,car) { uint32_t t_ = (a)^(b); (sum) = t_^(c); (car) = ((a)&(b)) | (t_&(c)); }
#define HA(a,b,sum,car)   { (sum) = (a)^(b); (car) = (a)&(b); }

// CSA: sum 16 one-bit inputs -> 5 bitplanes (count 0..16 per bit-lane)
__device__ __forceinline__ void csa16(const uint32_t* x, uint32_t* s) {
    uint32_t a0,a1,a2,a3,a4,b0,b1,b2,b3,b4;
    FA(x[0],x[1],x[2],a0,b0); FA(x[3],x[4],x[5],a1,b1); FA(x[6],x[7],x[8],a2,b2);
    FA(x[9],x[10],x[11],a3,b3); FA(x[12],x[13],x[14],a4,b4);
    uint32_t c0,c1,d0,d1,d2;
    FA(a0,a1,a2,c0,d0); FA(a3,a4,x[15],c1,d1);
    HA(c0,c1,s[0],d2);
    uint32_t e0,e1,e2,f0,f1,f2,f3;
    FA(b0,b1,b2,e0,f0); FA(b3,b4,d0,e1,f1);
    FA(e0,e1,d1,e2,f2);
    HA(e2,d2,s[1],f3);
    uint32_t g0,h0,h1;
    FA(f0,f1,f2,g0,h0);
    HA(g0,f3,s[2],h1);
    HA(h0,h1,s[3],s[4]);
}

__global__ __launch_bounds__(256, 4)
void encoder_kernel(const float* __restrict__ x,
                    const float* __restrict__ lw,
                    const float* __restrict__ cw,
                    float* __restrict__ out) {
    __shared__ __align__(16) uint32_t lwTT2[32 * 2];   // [l][wsel] sign words
    __shared__ __align__(16) uint32_t cwTT2[16 * 2];   // [c][wsel]
    __shared__ uint32_t sampC[T * SROW];               // count bytes, 9216 B
    __shared__ int part[8 * 32];

    const int tid = threadIdx.x;
    const int b = blockIdx.x >> 7;
    const int k = blockIdx.x & (NW - 1);   // outputs d = 32k+3 .. 32k+34 (mod D)

    // ---- Phase 0a: quantize own row (t = tid); keep 16 level indices in regs
    int l[16];
    {
        const float* xr = x + (b * T + tid) * C;
        #pragma unroll
        for (int m = 0; m < 4; ++m) {
            float4 v = *(const float4*)(xr + 4 * m);
            float vv[4] = {v.x, v.y, v.z, v.w};
            #pragma unroll
            for (int e = 0; e < 4; ++e) {
                float fi = (vv[e] / 20.0f) * 20.0f;   // exact replica of np ops
                int id = (int)rintf(fi);              // half-to-even == np.round
                id = min(max(id, 0), NUM_LEVELS - 1);
                l[4 * m + e] = id;
            }
        }
    }

    // ---- Phase 0b: bit-transpose weight signs for words k (wsel0), k+1 (wsel1)
    if (tid < 42) {
        const int wsel = tid / 21, lv = tid % 21;
        const float* src = lw + lv * D + 32 * ((k + wsel) & (NW - 1));
        uint32_t w = 0;
        #pragma unroll
        for (int m = 0; m < 8; ++m) {
            float4 v = *(const float4*)(src + 4 * m);
            w |= (__float_as_uint(v.x) >> 31) << (4 * m);
            w |= (__float_as_uint(v.y) >> 31) << (4 * m + 1);
            w |= (__float_as_uint(v.z) >> 31) << (4 * m + 2);
            w |= (__float_as_uint(v.w) >> 31) << (4 * m + 3);
        }
        lwTT2[2 * lv + wsel] = w;
    } else if (tid >= 64 && tid < 96) {
        const int i = tid - 64, wsel = i / 16, c = i % 16;
        const float* src = cw + c * D + 32 * ((k + wsel) & (NW - 1));
        uint32_t w = 0;
        #pragma unroll
        for (int m = 0; m < 8; ++m) {
            float4 v = *(const float4*)(src + 4 * m);
            w |= (__float_as_uint(v.x) >> 31) << (4 * m);
            w |= (__float_as_uint(v.y) >> 31) << (4 * m + 1);
            w |= (__float_as_uint(v.z) >> 31) << (4 * m + 2);
            w |= (__float_as_uint(v.w) >> 31) << (4 * m + 3);
        }
        cwTT2[2 * c + wsel] = w;
    }
    __syncthreads();

    // ---- Phase 1: bit-sliced popcount. bit_c[d] = lwbit[l_c][d] ^ cwbit[c][d];
    // count = CSA sum; store count bytes (col p: p<32 -> bit p of word k,
    // p=32..34 -> bits 0..2 of word k+1). samples value = 16-2c (applied in ph2).
    {
        uint32_t x0[16], x1[16];
        #pragma unroll
        for (int c = 0; c < 16; ++c) {
            uint2 g   = *(const uint2*)&lwTT2[2 * l[c]];   // ds_read_b64 gather
            uint2 cwp = *(const uint2*)&cwTT2[2 * c];      // broadcast
            x0[c] = g.x ^ cwp.x;
            x1[c] = g.y ^ cwp.y;
        }
        uint32_t p0[5], p1[5];
        csa16(x0, p0);
        csa16(x1, p1);
        uint32_t* row = &sampC[tid * SROW];
        #pragma unroll
        for (int g = 0; g < 8; ++g) {
            uint32_t cw32 = 0;
            #pragma unroll
            for (int kk = 0; kk < 5; ++kk) {
                uint32_t nib = (p0[kk] >> (4 * g)) & 0xFu;
                cw32 += ((nib * 0x204081u) & 0x01010101u) << kk;  // byte p = count bit kk
            }
            row[g] = cw32;
        }
        {
            uint32_t cw32 = 0;
            #pragma unroll
            for (int kk = 0; kk < 5; ++kk) {
                uint32_t nib = p1[kk] & 0x7u;
                cw32 += ((nib * 0x204081u) & 0x01010101u) << kk;
            }
            row[8] = cw32;
        }
    }
    __syncthreads();

    // ---- Phase 2: output d=32k+3+j uses cols j..j+3 at rows t..t+3.
    // m = 8 - c  (true sample = 2m; the 2^4 factor can't change the sign).
    const int j = tid & 31, seg = tid >> 5;
    const int t0 = seg * 32;
    const int rend = min(t0 + 34, 255);
    const int wbase = j >> 2;
    const int sh = (j & 3) * 8;
    int acc = 0;
    int q1 = 0, q2 = 0, q3 = 0;
    const uint32_t* sp = sampC + wbase;
    #pragma unroll
    for (int pr = 0; pr < 3; ++pr) {   // prime pipeline, rows t0..t0+2
        const int r = t0 + pr;
        uint32_t W0 = sp[r * SROW], W1 = sp[r * SROW + 1];
        uint32_t A = (uint32_t)(((((uint64_t)W1) << 32) | W0) >> sh); // bytes j..j+3
        int m0 = 8 - (int)(A & 0xFF);
        int m1 = 8 - (int)((A >> 8) & 0xFF);
        int m2 = 8 - (int)((A >> 16) & 0xFF);
        q3 = __mul24(q2, m2); q2 = __mul24(q1, m1); q1 = m0;
    }
    #pragma unroll 4
    for (int r = t0 + 3; r <= rend; ++r) {
        uint32_t W0 = sp[r * SROW], W1 = sp[r * SROW + 1];
        uint32_t A = (uint32_t)(((((uint64_t)W1) << 32) | W0) >> sh);
        int m0 = 8 - (int)(A & 0xFF);
        int m1 = 8 - (int)((A >> 8) & 0xFF);
        int m2 = 8 - (int)((A >> 16) & 0xFF);
        int m3 = 8 - (int)(A >> 24);
        acc += __mul24(q3, m3);            // window r-3 completes
        q3 = __mul24(q2, m2); q2 = __mul24(q1, m1); q1 = m0;
    }
    part[seg * 32 + j] = acc;
    __syncthreads();

    // ---- Final reduce + sign
    if (tid < 32) {
        int hv = 0;
        #pragma unroll
        for (int s = 0; s < 8; ++s) hv += part[s * 32 + tid];
        const int d = (32 * k + 3 + tid) & (D - 1);
        out[b * D + d] = hv > 0 ? 1.0f : -1.0f;   // hv==0 -> -1, matches ref
    }
}

extern "C" void kernel_launch(void* const* d_in, const int* in_sizes, int n_in,
                              void* d_out, int out_size, void* d_ws, size_t ws_size,
                              hipStream_t stream) {
    const float* x  = (const float*)d_in[0];
    const float* lw = (const float*)d_in[1];
    const float* cw = (const float*)d_in[2];
    float* out = (float*)d_out;
    encoder_kernel<<<dim3(BB * NW), dim3(256), 0, stream>>>(x, lw, cw, out);
}